// Round 6
// baseline (121.170 us; speedup 1.0000x reference)
//
#include <hip/hip_runtime.h>

// LSA, 2-kernel pipeline, occupancy-first restructure of R5 (R1-R5 evidence:
// all prior variants latency-bound at ~8 waves/CU, VALUBusy ~24%):
//   K_T : fmap[b][c][hw] f32 -> fT[b][n][c] bf16 + wvb=bf16(Wv)  (verbatim R4/R5)
//   K_F : per 2x16-px tile (1024 blocks, only 8.7 KB LDS -> up to 8 blocks/CU):
//         stencil taps read DIRECTLY from global fT (L1-resident footprint),
//         s -> LDS s_tile -> MFMA GEMM + residual (verbatim R5 math/mappings).
// B=4, C=128, H=64, W=128, L=25.

namespace {
constexpr int Bn = 4, Cn = 128, Hn = 64, Wn = 128, Ln = 25;
constexpr int HWn = Hn * Wn;  // 8192

typedef __attribute__((ext_vector_type(8))) short short8;
typedef __attribute__((ext_vector_type(4))) float f32x4;

__device__ inline unsigned short f2bf(float f) {
    unsigned u = __float_as_uint(f);
    return (unsigned short)((u + 0x7fffu + ((u >> 16) & 1u)) >> 16);  // RNE
}

// ---------------- K_T: transpose fmap -> fT (bf16), convert Wv (verbatim) ----
__global__ __launch_bounds__(256) void k_transpose(
    const float* __restrict__ fmap, const float* __restrict__ Wv,
    unsigned short* __restrict__ fT, unsigned short* __restrict__ wvb)
{
    __shared__ float tile[Cn][33];
    const int tid = threadIdx.x;
    const int b = blockIdx.y;
    const int n0 = blockIdx.x * 32;

    if (blockIdx.x == 0 && b == 0) {
        for (int i = tid; i < Cn * Cn; i += 256) wvb[i] = f2bf(Wv[i]);
    }
    for (int i = tid; i < Cn * 8; i += 256) {
        int c = i >> 3, q = i & 7;
        float4 v = *(const float4*)&fmap[((size_t)(b * Cn + c)) * HWn + n0 + q * 4];
        tile[c][q * 4 + 0] = v.x; tile[c][q * 4 + 1] = v.y;
        tile[c][q * 4 + 2] = v.z; tile[c][q * 4 + 3] = v.w;
    }
    __syncthreads();
    for (int i = tid; i < 32 * 64; i += 256) {
        int n = i >> 6, cp = i & 63;
        unsigned lo = f2bf(tile[2 * cp][n]), hi = f2bf(tile[2 * cp + 1][n]);
        *(unsigned*)&fT[((size_t)(b * HWn + n0 + n)) * Cn + 2 * cp] = lo | (hi << 16);
    }
}

// ---------------- K_F: stencil (global taps) + MFMA GEMM, small-LDS --------
constexpr int STS = 136;  // s_tile row stride in halves (272 B)

__global__ __launch_bounds__(256, 4) void k_fused(
    const unsigned short* __restrict__ fT, const float* __restrict__ attn,
    const unsigned short* __restrict__ wvb, const float* __restrict__ fmap,
    const float* __restrict__ gamma, float* __restrict__ out)
{
    __shared__ unsigned short s_tile[32 * STS];  // 8.7 KB only

    const int tid = threadIdx.x;
    const int b = blockIdx.z;
    const int x0 = blockIdx.x * 16;
    const int y0 = blockIdx.y * 2;
    const float g = gamma[0];

    // thread = pixel (yi, xi) x 16-channel group kq
    const int xi = tid & 15, kq = (tid >> 4) & 7, yi = tid >> 7;
    const int y = y0 + yi;
    const int n = y * Wn + x0 + xi;

    float acc[16];
#pragma unroll
    for (int j = 0; j < 16; ++j) acc[j] = 0.f;

    const float* att_row = &attn[((size_t)b * HWn + n) * Ln];
#pragma unroll
    for (int l = 0; l < Ln; ++l) {
        const int dy = l / 5, dx = l % 5;
        const float a = att_row[l];
        const int ry = min(max(y + dy - 2, 0), Hn - 1);
        const int gx = min(max(x0 + xi + dx - 2, 0), Wn - 1);
        const unsigned short* row = &fT[((size_t)(b * HWn + ry * Wn + gx)) * Cn + kq * 16];
        uint4 u0 = *(const uint4*)&row[0];
        uint4 u1 = *(const uint4*)&row[8];
        const unsigned w0[4] = {u0.x, u0.y, u0.z, u0.w};
        const unsigned w1[4] = {u1.x, u1.y, u1.z, u1.w};
#pragma unroll
        for (int e = 0; e < 4; ++e) {
            acc[2 * e + 0] += a * __uint_as_float(w0[e] << 16);
            acc[2 * e + 1] += a * __uint_as_float(w0[e] & 0xffff0000u);
            acc[8 + 2 * e + 0] += a * __uint_as_float(w1[e] << 16);
            acc[8 + 2 * e + 1] += a * __uint_as_float(w1[e] & 0xffff0000u);
        }
    }
    // pack 16 ch -> bf16 pairs into s_tile (same packing as R5)
    {
        unsigned short* dst = &s_tile[(yi * 16 + xi) * STS + kq * 16];
        unsigned pk[8];
#pragma unroll
        for (int e = 0; e < 8; ++e)
            pk[e] = (unsigned)f2bf(acc[2 * e]) | ((unsigned)f2bf(acc[2 * e + 1]) << 16);
        uint4 v0; v0.x = pk[0]; v0.y = pk[1]; v0.z = pk[2]; v0.w = pk[3];
        uint4 v1; v1.x = pk[4]; v1.y = pk[5]; v1.z = pk[6]; v1.w = pk[7];
        *(uint4*)&dst[0] = v0;
        *(uint4*)&dst[8] = v1;
    }
    __syncthreads();

    // ---- GEMM + epilogue (R5 mappings; 2 px-rows x 2 mg-halves per block) ----
    const int wave = tid >> 6, lane = tid & 63;
    const int m16 = lane & 15, q = lane >> 4;
    const int wrow = wave & 1;    // pixel row within tile
    const int mhalf = wave >> 1;  // channel half (mg 0-3 / 4-7)

    short8 bfrag[4];
    const unsigned short* srow = &s_tile[(wrow * 16 + m16) * STS + q * 8];
#pragma unroll
    for (int kk = 0; kk < 4; ++kk) bfrag[kk] = *(const short8*)(srow + kk * 32);

#pragma unroll
    for (int t = 0; t < 4; ++t) {
        const int mg = mhalf * 4 + t;
        const unsigned short* arow = &wvb[(size_t)(mg * 16 + m16) * Cn + q * 8];
        f32x4 acc2 = {0.f, 0.f, 0.f, 0.f};
#pragma unroll
        for (int kk = 0; kk < 4; ++kk) {
            short8 af = *(const short8*)(arow + kk * 32);
            acc2 = __builtin_amdgcn_mfma_f32_16x16x32_bf16(af, bfrag[kk], acc2, 0, 0, 0);
        }
        // D: col = lane&15 = px-in-row, row = q*4+r = channel-within-16
#pragma unroll
        for (int r = 0; r < 4; ++r) {
            const int c = mg * 16 + q * 4 + r;
            const size_t idx = ((size_t)(b * Cn + c)) * HWn + (y0 + wrow) * Wn + x0 + m16;
            out[idx] = fmap[idx] + g * acc2[r];
        }
    }
}
}  // namespace

extern "C" void kernel_launch(void* const* d_in, const int* in_sizes, int n_in,
                              void* d_out, int out_size, void* d_ws, size_t ws_size,
                              hipStream_t stream) {
    const float* attn  = (const float*)d_in[0];
    const float* fmap  = (const float*)d_in[1];
    const float* Wv    = (const float*)d_in[2];
    const float* gamma = (const float*)d_in[3];
    float* out = (float*)d_out;

    // ws layout: fT 8.39 MB | wvb 32 KB
    unsigned short* fT  = (unsigned short*)d_ws;
    unsigned short* wvb = fT + (size_t)Bn * HWn * Cn;

    dim3 gT(HWn / 32, Bn);          // 256 x 4
    k_transpose<<<gT, 256, 0, stream>>>(fmap, Wv, fT, wvb);

    dim3 gF(Wn / 16, Hn / 2, Bn);   // 8 x 32 x 4 = 1024 blocks
    k_fused<<<gF, 256, 0, stream>>>(fT, attn, wvb, fmap, gamma, out);
}

// Round 7
// 116.933 us; speedup vs baseline: 1.0362x; 1.0362x over previous
//
#include <hip/hip_runtime.h>

// LSA 2-kernel pipeline, R7: R5's coalesced staging + R6's occupancy.
//   K_T : fmap[b][c][hw] f32 -> fT[b][n][c] bf16 + wvb=bf16(Wv)  (verbatim, verified)
//   K_F : per 4x8-px tile, 34 KB LDS -> 4 blocks/CU (16 waves/CU):
//         coalesced halo stage (8x12 px rows) -> conflict-free LDS stencil
//         (verbatim R6 inner math) -> s_tile -> MFMA GEMM + residual (verified).
// B=4, C=128, H=64, W=128, L=25.

namespace {
constexpr int Bn = 4, Cn = 128, Hn = 64, Wn = 128, Ln = 25;
constexpr int HWn = Hn * Wn;  // 8192

typedef __attribute__((ext_vector_type(8))) short short8;
typedef __attribute__((ext_vector_type(4))) float f32x4;

__device__ inline unsigned short f2bf(float f) {
    unsigned u = __float_as_uint(f);
    return (unsigned short)((u + 0x7fffu + ((u >> 16) & 1u)) >> 16);  // RNE
}

// ---------------- K_T: transpose fmap -> fT (bf16), convert Wv (verbatim) ----
__global__ __launch_bounds__(256) void k_transpose(
    const float* __restrict__ fmap, const float* __restrict__ Wv,
    unsigned short* __restrict__ fT, unsigned short* __restrict__ wvb)
{
    __shared__ float tile[Cn][33];
    const int tid = threadIdx.x;
    const int b = blockIdx.y;
    const int n0 = blockIdx.x * 32;

    if (blockIdx.x == 0 && b == 0) {
        for (int i = tid; i < Cn * Cn; i += 256) wvb[i] = f2bf(Wv[i]);
    }
    for (int i = tid; i < Cn * 8; i += 256) {
        int c = i >> 3, q = i & 7;
        float4 v = *(const float4*)&fmap[((size_t)(b * Cn + c)) * HWn + n0 + q * 4];
        tile[c][q * 4 + 0] = v.x; tile[c][q * 4 + 1] = v.y;
        tile[c][q * 4 + 2] = v.z; tile[c][q * 4 + 3] = v.w;
    }
    __syncthreads();
    for (int i = tid; i < 32 * 64; i += 256) {
        int n = i >> 6, cp = i & 63;
        unsigned lo = f2bf(tile[2 * cp][n]), hi = f2bf(tile[2 * cp + 1][n]);
        *(unsigned*)&fT[((size_t)(b * HWn + n0 + n)) * Cn + 2 * cp] = lo | (hi << 16);
    }
}

// ---------------- K_F: small-tile fused stencil + MFMA GEMM ----------------
constexpr int TY = 4, TX = 8;    // 32 px per block
constexpr int HYr = 8, HXc = 12; // halo: rows y0-2..y0+5, cols x0-2..x0+9
constexpr int RSH = 132;         // halo row stride in halves (264 B, 66 dwords: 2-way free)
constexpr int STS = 136;         // s_tile row stride in halves

__global__ __launch_bounds__(256, 4) void k_fused(
    const unsigned short* __restrict__ fT, const float* __restrict__ attn,
    const unsigned short* __restrict__ wvb, const float* __restrict__ fmap,
    const float* __restrict__ gamma, float* __restrict__ out)
{
    __shared__ unsigned short hs[HYr * HXc * RSH];  // 25.3 KB
    __shared__ unsigned short s_tile[32 * STS];     // 8.7 KB

    const int tid = threadIdx.x;
    const int b = blockIdx.z;
    const int x0 = blockIdx.x * TX;
    const int y0 = blockIdx.y * TY;
    const float g = gamma[0];

    // ---- stage halo, fully coalesced (16 lanes = one 256B px row) ----
    for (int i = tid; i < HYr * HXc * 16; i += 256) {
        int hp = i >> 4, t = i & 15;
        int hy = hp / HXc, hx = hp - hy * HXc;
        int ry = min(max(y0 + hy - 2, 0), Hn - 1);
        int gx = min(max(x0 + hx - 2, 0), Wn - 1);
        *(uint4*)&hs[hp * RSH + t * 8] =
            *(const uint4*)&fT[((size_t)(b * HWn + ry * Wn + gx)) * Cn + t * 8];
    }
    __syncthreads();

    // ---- stencil (R6-verified inner math; taps now from LDS) ----
    const int xi = tid & 7, kq = (tid >> 3) & 7, yi = tid >> 6;
    const int n = (y0 + yi) * Wn + x0 + xi;
    const float* att_row = &attn[((size_t)b * HWn + n) * Ln];

    float acc[16];
#pragma unroll
    for (int j = 0; j < 16; ++j) acc[j] = 0.f;

#pragma unroll
    for (int l = 0; l < Ln; ++l) {
        const int dy = l / 5, dx = l % 5;
        const float a = att_row[l];
        const unsigned short* row = &hs[((yi + dy) * HXc + (xi + dx)) * RSH + kq * 16];
        uint4 u0 = *(const uint4*)&row[0];
        uint4 u1 = *(const uint4*)&row[8];
        const unsigned w0[4] = {u0.x, u0.y, u0.z, u0.w};
        const unsigned w1[4] = {u1.x, u1.y, u1.z, u1.w};
#pragma unroll
        for (int e = 0; e < 4; ++e) {
            acc[2 * e + 0] += a * __uint_as_float(w0[e] << 16);
            acc[2 * e + 1] += a * __uint_as_float(w0[e] & 0xffff0000u);
            acc[8 + 2 * e + 0] += a * __uint_as_float(w1[e] << 16);
            acc[8 + 2 * e + 1] += a * __uint_as_float(w1[e] & 0xffff0000u);
        }
    }
    // pack 16 ch -> s_tile (verbatim R6 packing)
    {
        unsigned short* dst = &s_tile[(yi * TX + xi) * STS + kq * 16];
        unsigned pk[8];
#pragma unroll
        for (int e = 0; e < 8; ++e)
            pk[e] = (unsigned)f2bf(acc[2 * e]) | ((unsigned)f2bf(acc[2 * e + 1]) << 16);
        uint4 v0; v0.x = pk[0]; v0.y = pk[1]; v0.z = pk[2]; v0.w = pk[3];
        uint4 v1; v1.x = pk[4]; v1.y = pk[5]; v1.z = pk[6]; v1.w = pk[7];
        *(uint4*)&dst[0] = v0;
        *(uint4*)&dst[8] = v1;
    }
    __syncthreads();

    // ---- GEMM + epilogue (verified R5/R6 wave structure) ----
    const int wave = tid >> 6, lane = tid & 63;
    const int m16 = lane & 15, q = lane >> 4;
    const int ntile = wave & 1;   // px group 0..15 / 16..31
    const int mhalf = wave >> 1;  // channel half (mg 0-3 / 4-7)

    short8 bfrag[4];
    const unsigned short* srow = &s_tile[(ntile * 16 + m16) * STS + q * 8];
#pragma unroll
    for (int kk = 0; kk < 4; ++kk) bfrag[kk] = *(const short8*)(srow + kk * 32);

    const int p = ntile * 16 + m16;       // local px id
    const int py = p >> 3, px = p & 7;    // within-tile (row, col)

#pragma unroll
    for (int t = 0; t < 4; ++t) {
        const int mg = mhalf * 4 + t;
        const unsigned short* arow = &wvb[(size_t)(mg * 16 + m16) * Cn + q * 8];
        f32x4 acc2 = {0.f, 0.f, 0.f, 0.f};
#pragma unroll
        for (int kk = 0; kk < 4; ++kk) {
            short8 af = *(const short8*)(arow + kk * 32);
            acc2 = __builtin_amdgcn_mfma_f32_16x16x32_bf16(af, bfrag[kk], acc2, 0, 0, 0);
        }
        // D: col = lane&15 = px-within-16-group, row = q*4+r = channel-within-16
#pragma unroll
        for (int r = 0; r < 4; ++r) {
            const int c = mg * 16 + q * 4 + r;
            const size_t idx = ((size_t)(b * Cn + c)) * HWn + (y0 + py) * Wn + x0 + px;
            out[idx] = fmap[idx] + g * acc2[r];
        }
    }
}
}  // namespace

extern "C" void kernel_launch(void* const* d_in, const int* in_sizes, int n_in,
                              void* d_out, int out_size, void* d_ws, size_t ws_size,
                              hipStream_t stream) {
    const float* attn  = (const float*)d_in[0];
    const float* fmap  = (const float*)d_in[1];
    const float* Wv    = (const float*)d_in[2];
    const float* gamma = (const float*)d_in[3];
    float* out = (float*)d_out;

    // ws layout: fT 8.39 MB | wvb 32 KB
    unsigned short* fT  = (unsigned short*)d_ws;
    unsigned short* wvb = fT + (size_t)Bn * HWn * Cn;

    dim3 gT(HWn / 32, Bn);          // 256 x 4
    k_transpose<<<gT, 256, 0, stream>>>(fmap, Wv, fT, wvb);

    dim3 gF(Wn / TX, Hn / TY, Bn);  // 16 x 16 x 4 = 1024 blocks (4/CU, one round)
    k_fused<<<gF, 256, 0, stream>>>(fT, attn, wvb, fmap, gamma, out);
}